// Round 7
// baseline (270.706 us; speedup 1.0000x reference)
//
#include <hip/hip_runtime.h>
#include <hip/hip_bf16.h>

// Problem constants (fixed by reference): B=8, C=128, N=M=4096, OUT=128
#define BATCH 8
#define CDIM 128
#define NDIM 4096

typedef __bf16 bf16x8 __attribute__((ext_vector_type(8)));
typedef float f32x4 __attribute__((ext_vector_type(4)));
typedef float f32x16 __attribute__((ext_vector_type(16)));
typedef unsigned u32x4 __attribute__((ext_vector_type(4)));

// workspace layout (bytes)
// Qt: bf16 [8][4096][128] row-major, normalized * log2(e)
// Kf: fragment-major K: chunk addr = KT_OFF + b*1MB + body*16384 + nt*8192
//     + s*1024 + lane*16 ; element n = body*64+nt*32+l31, c = s*16+hf*8+j
// Vf: fragment-major V: chunk addr = VB_OFF + b*1MB + body*16384 + nt*8192
//     + (ca*2+t)*1024 + lane*16 ; element c = ca*32+l31, n = body*64+nt*32+t*16+hf*8+j
#define QT_OFF 0u
#define KT_OFF 8388608u
#define VB_OFF 16777216u
#define WT_OFF 25165824u               // bf16 [128][128] wT[o][c]
#define SC_OFF (WT_OFF + 32768u)       // f32 [128] scale = gamma*rsqrt(var+eps)
#define BI_OFF (SC_OFF + 512u)         // f32 [128] bias  = beta - mean*scale

__device__ __forceinline__ f32x4 mfma16(bf16x8 a, bf16x8 b, f32x4 c) {
    return __builtin_amdgcn_mfma_f32_16x16x32_bf16(a, b, c, 0, 0, 0);
}
__device__ __forceinline__ f32x16 mfma32(bf16x8 a, bf16x8 b, f32x16 c) {
    return __builtin_amdgcn_mfma_f32_32x32x16_bf16(a, b, c, 0, 0, 0);
}

__device__ __forceinline__ unsigned pack2bf(float a, float b) {
    unsigned short ul = __builtin_bit_cast(unsigned short, (__bf16)a);
    unsigned short uh = __builtin_bit_cast(unsigned short, (__bf16)b);
    return (unsigned)ul | ((unsigned)uh << 16);
}

// ---------------------------------------------------------------------------
// Pass 1: per-column L2 normalize over C; emit fragment-major Kf/Vf (z==0)
// and row-major Qt scaled by log2(e) (z==1).  One block also folds W/BN.
// ---------------------------------------------------------------------------
__global__ __launch_bounds__(256) void prep_nt(const float* __restrict__ input,
                                               const float* __restrict__ tg,
                                               const float* __restrict__ wgt,
                                               const float* __restrict__ gamma,
                                               const float* __restrict__ beta,
                                               const float* __restrict__ mean,
                                               const float* __restrict__ var,
                                               void* __restrict__ ws) {
    __shared__ float Tt[64][129];     // [n-local][c], pitch 129
    __shared__ float psum[4][64];
    __shared__ float rn[64];
    const int n0 = blockIdx.x * 64;
    const int b  = blockIdx.y;
    const int tid = threadIdx.x;
    const float* src = (blockIdx.z == 0 ? input : tg) + (size_t)b * CDIM * NDIM;

    #pragma unroll
    for (int i = 0; i < 8; ++i) {
        int f = tid + i * 256;
        int c = f >> 4, j4 = f & 15;
        float4 v = *(const float4*)(src + (size_t)c * NDIM + n0 + j4 * 4);
        Tt[j4 * 4 + 0][c] = v.x;
        Tt[j4 * 4 + 1][c] = v.y;
        Tt[j4 * 4 + 2][c] = v.z;
        Tt[j4 * 4 + 3][c] = v.w;
    }
    __syncthreads();
    {
        int j = tid & 63, part = tid >> 6;
        float ss = 0.f;
        #pragma unroll 8
        for (int c = part * 32; c < part * 32 + 32; ++c) { float x = Tt[j][c]; ss += x * x; }
        psum[part][j] = ss;
    }
    __syncthreads();
    if (tid < 64) {
        float s = psum[0][tid] + psum[1][tid] + psum[2][tid] + psum[3][tid];
        rn[tid] = 1.0f / fmaxf(sqrtf(s), 1e-12f);
    }
    __syncthreads();

    if (blockIdx.z == 0) {
        char* kfb = (char*)ws + KT_OFF + (size_t)b * 1048576u + (size_t)blockIdx.x * 16384u;
        char* vfb = (char*)ws + VB_OFF + (size_t)b * 1048576u + (size_t)blockIdx.x * 16384u;
        #pragma unroll
        for (int i = 0; i < 4; ++i) {
            int q = tid + i * 256;             // 0..1023 chunk id
            int lane = q & 63, l31 = q & 31, hf = (q >> 5) & 1;
            // K chunk: (nt, s, lane)
            int s = (q >> 6) & 7, ntk = q >> 9;
            int nl = ntk * 32 + l31;
            float r = rn[nl];
            int c0 = s * 16 + hf * 8;
            uint4 pk;
            pk.x = pack2bf(Tt[nl][c0 + 0] * r, Tt[nl][c0 + 1] * r);
            pk.y = pack2bf(Tt[nl][c0 + 2] * r, Tt[nl][c0 + 3] * r);
            pk.z = pack2bf(Tt[nl][c0 + 4] * r, Tt[nl][c0 + 5] * r);
            pk.w = pack2bf(Tt[nl][c0 + 6] * r, Tt[nl][c0 + 7] * r);
            *(uint4*)(kfb + ntk * 8192 + s * 1024 + lane * 16) = pk;
            // V chunk: (nt, ca, t, lane)
            int tt = (q >> 6) & 1, ca = (q >> 7) & 3, ntv = q >> 9;
            int c = ca * 32 + l31;
            int nv = ntv * 32 + tt * 16 + hf * 8;
            uint4 pv;
            pv.x = pack2bf(Tt[nv + 0][c], Tt[nv + 1][c]);
            pv.y = pack2bf(Tt[nv + 2][c], Tt[nv + 3][c]);
            pv.z = pack2bf(Tt[nv + 4][c], Tt[nv + 5][c]);
            pv.w = pack2bf(Tt[nv + 6][c], Tt[nv + 7][c]);
            *(uint4*)(vfb + ntv * 8192 + (ca * 2 + tt) * 1024 + lane * 16) = pv;
        }
    } else {
        __hip_bfloat16* dstT = (__hip_bfloat16*)((char*)ws + QT_OFF)
                               + ((size_t)b * NDIM + n0) * CDIM;
        #pragma unroll
        for (int i = 0; i < 8; ++i) {
            int f = tid + i * 256;
            int j = f >> 5, c4 = f & 31;
            float r = rn[j] * 1.44269504f;     // fold log2(e): P = 2^(S*log2e)
            float4 v = *(const float4*)&Tt[j][c4 * 4];
            uint2 pk; pk.x = pack2bf(v.x * r, v.y * r); pk.y = pack2bf(v.z * r, v.w * r);
            *(uint2*)((unsigned short*)dstT + (size_t)j * CDIM + c4 * 4) = pk;
        }
        if (blockIdx.x == 0 && b == 0) {
            __hip_bfloat16* wT = (__hip_bfloat16*)((char*)ws + WT_OFF);
            float* sc = (float*)((char*)ws + SC_OFF);
            float* bi = (float*)((char*)ws + BI_OFF);
            #pragma unroll
            for (int i = 0; i < 64; ++i) {
                int f = tid + i * 256;
                int c = f >> 7, o = f & 127;
                wT[o * 128 + c] = __hip_bfloat16(wgt[c * 128 + o]);
            }
            if (tid < 128) {
                float inv = rsqrtf(var[tid] + 1e-5f);
                float s = inv * gamma[tid];
                sc[tid] = s;
                bi[tid] = beta[tid] - mean[tid] * s;
            }
        }
    }
}

// ---------------------------------------------------------------------------
// Pass 2 (flash7): BARRIER-FREE main loop, NO LDS staging. K/V operands are
// streamed as pre-swizzled fragments via contiguous 1-KB global loads
// (L1 absorbs the 4x mt-wave redundancy; per-XCD L2 holds the whole batch).
// Grid 256 (1 block/CU), batch = bx&7 (XCD-pinned), m-tile 128.
// 512 thr = 8 waves: nt = w&1 (32-n slice of each 64-n body), mt = w>>1.
// Per body: 8 V loads + 8 next-K loads in flight across S-MFMA + exp chain;
// P stays in registers (C-layout -> B-operand via shfl_xor(32) half-swap).
// LDS only in epilogue: slabs 4x16512 @0, sAgg bf16[128][128] @66560.
// ---------------------------------------------------------------------------
__global__ __launch_bounds__(512, 2) void flash7(const void* __restrict__ ws_,
                                                 float* __restrict__ out) {
    extern __shared__ char smem[];
    const char* ws = (const char*)ws_;
    const __hip_bfloat16* Qt = (const __hip_bfloat16*)(ws + QT_OFF);
    const __hip_bfloat16* wT = (const __hip_bfloat16*)(ws + WT_OFF);
    const float* scale = (const float*)(ws + SC_OFF);
    const float* bias  = (const float*)(ws + BI_OFF);

    const int bx = blockIdx.x;
    const int b  = bx & 7;
    const int m0 = (bx >> 3) * 128;
    const int tid = threadIdx.x;
    const int w = tid >> 6, lane = tid & 63;
    const int hf = lane >> 5;
    const int l31 = lane & 31;
    const int nt = w & 1;
    const int mt = w >> 1;

    // resident Q B-frags: col m = m0 + mt*32 + l31
    bf16x8 qb[8];
    {
        const char* qrow = (const char*)Qt + ((size_t)b * NDIM + m0 + mt * 32 + l31) * 256 + hf * 16;
        #pragma unroll
        for (int s = 0; s < 8; ++s) qb[s] = *(const bf16x8*)(qrow + s * 32);
    }

    // fragment stream pointers (advance 16384 B per 64-n body)
    const char* kp = ws + KT_OFF + (size_t)b * 1048576u + nt * 8192 + lane * 16;
    const char* vp = ws + VB_OFF + (size_t)b * 1048576u + nt * 8192 + lane * 16;

    f32x16 oacc[4];
    #pragma unroll
    for (int ca = 0; ca < 4; ++ca)
        #pragma unroll
        for (int i = 0; i < 16; ++i) oacc[ca][i] = 0.f;
    float lacc = 0.f;

    auto make_pf = [&](const f32x16& st, bf16x8 pf[2]) {
        unsigned d[8];
        float lsum = 0.f;
        #pragma unroll
        for (int rq = 0; rq < 4; ++rq) {
            float e0 = exp2f(st[rq * 4 + 0]);
            float e1 = exp2f(st[rq * 4 + 1]);
            float e2 = exp2f(st[rq * 4 + 2]);
            float e3 = exp2f(st[rq * 4 + 3]);
            lsum += (e0 + e1) + (e2 + e3);
            d[rq * 2 + 0] = pack2bf(e0, e1);
            d[rq * 2 + 1] = pack2bf(e2, e3);
        }
        lacc += lsum;
        unsigned o[8];
        #pragma unroll
        for (int j = 0; j < 8; ++j) o[j] = (unsigned)__shfl_xor((int)d[j], 32, 64);
        #pragma unroll
        for (int t = 0; t < 2; ++t) {
            u32x4 tv;
            tv.x = hf ? o[4 * t + 2] : d[4 * t + 0];
            tv.y = hf ? o[4 * t + 3] : d[4 * t + 1];
            tv.z = hf ? d[4 * t + 2] : o[4 * t + 0];
            tv.w = hf ? d[4 * t + 3] : o[4 * t + 1];
            pf[t] = __builtin_bit_cast(bf16x8, tv);
        }
    };

    // software pipeline: K fragments prefetched one body ahead
    bf16x8 kA[8], kB[8];
    #pragma unroll
    for (int s = 0; s < 8; ++s) kA[s] = *(const bf16x8*)(kp + s * 1024);
    kp += 16384;

    auto step = [&](bf16x8* kc, bf16x8* kn) {
        // V loads for this body (land during S + exp)
        bf16x8 vf[8];
        #pragma unroll
        for (int u = 0; u < 8; ++u) vf[u] = *(const bf16x8*)(vp + u * 1024);
        vp += 16384;
        // K loads for NEXT body (land during exp + PV + next S)
        #pragma unroll
        for (int s = 0; s < 8; ++s) kn[s] = *(const bf16x8*)(kp + s * 1024);
        kp += 16384;

        // S^T = K.Q^T : D[n_local][m], 32x32, k=128
        f32x16 st;
        #pragma unroll
        for (int i = 0; i < 16; ++i) st[i] = 0.f;
        #pragma unroll
        for (int s = 0; s < 8; ++s) st = mfma32(kc[s], qb[s], st);

        bf16x8 pf[2];
        make_pf(st, pf);

        // O^T += V.P^T
        #pragma unroll
        for (int ca = 0; ca < 4; ++ca) {
            oacc[ca] = mfma32(vf[ca * 2 + 0], pf[0], oacc[ca]);
            oacc[ca] = mfma32(vf[ca * 2 + 1], pf[1], oacc[ca]);
        }
    };

    for (int it = 0; it < 32; ++it) {
        step(kA, kB);
        step(kB, kA);
    }
    // (final prefetch reads 16 KB past this batch's Kf — valid ws memory, discarded)

    // ---- epilogue (verified structure from flash6) ----
    float lw = lacc + __shfl_xor(lacc, 32, 64);
    __syncthreads();                               // E0: all waves done with loop
    char* slab = smem + mt * 16512;                // 4 slabs: 16 KB O + 128 B l
    if (nt == 1) {
        float4* dst = (float4*)slab;
        #pragma unroll
        for (int ca = 0; ca < 4; ++ca)
            #pragma unroll
            for (int rq = 0; rq < 4; ++rq) {
                float4 t = { oacc[ca][rq * 4 + 0], oacc[ca][rq * 4 + 1],
                             oacc[ca][rq * 4 + 2], oacc[ca][rq * 4 + 3] };
                dst[(ca * 4 + rq) * 64 + lane] = t;
            }
        if (lane < 32) ((float*)(slab + 16384))[l31] = lw;
    }
    __syncthreads();                               // E1
    char* sAgg = smem + 66560;                     // bf16 [128 m][128 c] swz
    if (nt == 0) {
        float linv = 1.0f / (lw + ((const float*)(slab + 16384))[l31]);
        const float4* srcp = (const float4*)slab;
        int m = mt * 32 + l31;
        char* aggRow = sAgg + m * 256;
        const int mx = (m & 7) << 1;
        #pragma unroll
        for (int ca = 0; ca < 4; ++ca)
            #pragma unroll
            for (int rq = 0; rq < 4; ++rq) {
                float4 ov = srcp[(ca * 4 + rq) * 64 + lane];
                float v0 = (oacc[ca][rq * 4 + 0] + ov.x) * linv;
                float v1 = (oacc[ca][rq * 4 + 1] + ov.y) * linv;
                float v2 = (oacc[ca][rq * 4 + 2] + ov.z) * linv;
                float v3 = (oacc[ca][rq * 4 + 3] + ov.w) * linv;
                int cq = ca * 8 + rq * 2 + hf;
                uint2 pk; pk.x = pack2bf(v0, v1); pk.y = pack2bf(v2, v3);
                *(uint2*)(aggRow + ((cq ^ mx) * 8)) = pk;
            }
    }
    __syncthreads();                               // E2: sAgg ready

    // projection (16x16 MFMA): wave -> m-slice w*16, all 128 o
    const int li = lane & 15, q = lane >> 4;
    const int pm = w * 16 + li;
    f32x4 racc[8];
    #pragma unroll
    for (int ob = 0; ob < 8; ++ob) { racc[ob][0]=0.f; racc[ob][1]=0.f; racc[ob][2]=0.f; racc[ob][3]=0.f; }
    #pragma unroll
    for (int ks = 0; ks < 4; ++ks) {
        int slot8 = ((ks * 4 + q) * 2) ^ ((li & 7) << 1);
        bf16x8 af = *(const bf16x8*)(sAgg + pm * 256 + slot8 * 8);
        #pragma unroll
        for (int ob = 0; ob < 8; ++ob) {
            bf16x8 wf = *(const bf16x8*)((const char*)wT + (ob * 16 + li) * 256 + ks * 64 + q * 16);
            racc[ob] = mfma16(af, wf, racc[ob]);
        }
    }

    // LeakyReLU + BN(eval) + direct float4 stores (racc rows = 4 consecutive m)
    float* outb = out + (size_t)b * CDIM * NDIM + m0 + w * 16;
    #pragma unroll
    for (int ob = 0; ob < 8; ++ob) {
        int o = ob * 16 + li;
        float sc = scale[o], bi = bias[o];
        float4 vst;
        float v0 = racc[ob][0]; v0 = (v0 >= 0.f) ? v0 : 0.01f * v0; vst.x = v0 * sc + bi;
        float v1 = racc[ob][1]; v1 = (v1 >= 0.f) ? v1 : 0.01f * v1; vst.y = v1 * sc + bi;
        float v2 = racc[ob][2]; v2 = (v2 >= 0.f) ? v2 : 0.01f * v2; vst.z = v2 * sc + bi;
        float v3 = racc[ob][3]; v3 = (v3 >= 0.f) ? v3 : 0.01f * v3; vst.w = v3 * sc + bi;
        *(float4*)(outb + (size_t)o * NDIM + q * 4) = vst;
    }
}

extern "C" void kernel_launch(void* const* d_in, const int* in_sizes, int n_in,
                              void* d_out, int out_size, void* d_ws, size_t ws_size,
                              hipStream_t stream) {
    const float* input  = (const float*)d_in[0];
    const float* tg     = (const float*)d_in[1];
    const float* weight = (const float*)d_in[2];
    const float* gamma  = (const float*)d_in[3];
    const float* beta   = (const float*)d_in[4];
    const float* rmean  = (const float*)d_in[5];
    const float* rvar   = (const float*)d_in[6];
    float* out = (float*)d_out;

    (void)in_sizes; (void)n_in; (void)out_size; (void)ws_size;

    hipFuncSetAttribute(reinterpret_cast<const void*>(flash7),
                        hipFuncAttributeMaxDynamicSharedMemorySize, 99328);

    dim3 gprep(NDIM / 64, BATCH, 2);
    prep_nt<<<gprep, 256, 0, stream>>>(input, tg, weight, gamma, beta, rmean, rvar, d_ws);
    flash7<<<dim3(256), 512, 99328, stream>>>(d_ws, out);
}